// Round 3
// baseline (672.633 us; speedup 1.0000x reference)
//
#include <hip/hip_runtime.h>
#include <hip/hip_fp16.h>

#define HH 352
#define WW 1216
#define HW (HH*WW)
#define NPIX (2*HW)      // 856064
#define NITER 18

// ---------------------------------------------------------------------------
// Kernel A: 3x3 conv (9->27ch, pad 1) over guidance; write f32 outputs:
//   out_off[B,18,H,W] = f32(f16(oa[0..17]))       (offset1, fp16-quantized)
//   out_aff[B,9,H,W]  = f32(f16(softmax(oa[18..26])))  (aff1)
// ---------------------------------------------------------------------------
__global__ __launch_bounds__(256) void conv_kernel(
    const float* __restrict__ g,
    const float* __restrict__ cw,
    const float* __restrict__ cb,
    float* __restrict__ out_off,
    float* __restrict__ out_aff)
{
    __shared__ float sw[27 * 81];
    __shared__ float sb[27];
    for (int i = threadIdx.x; i < 27 * 81; i += 256) sw[i] = cw[i];
    if (threadIdx.x < 27) sb[threadIdx.x] = cb[threadIdx.x];
    __syncthreads();

    int p = blockIdx.x * 256 + threadIdx.x;
    if (p >= NPIX) return;
    int b = p / HW;
    int r = p - b * HW;
    int y = r / WW;
    int x = r - y * WW;

    float acc[27];
#pragma unroll
    for (int co = 0; co < 27; ++co) acc[co] = sb[co];

    const float* gb = g + (size_t)b * 9 * HW;
    for (int ci = 0; ci < 9; ++ci) {
#pragma unroll
        for (int t = 0; t < 9; ++t) {
            int yy = y + t / 3 - 1;
            int xx = x + t % 3 - 1;
            float v = ((unsigned)yy < HH && (unsigned)xx < WW)
                          ? gb[(size_t)ci * HW + yy * WW + xx] : 0.f;
#pragma unroll
            for (int co = 0; co < 27; ++co)
                acc[co] = fmaf(v, sw[co * 81 + ci * 9 + t], acc[co]);
        }
    }

    // offsets: fp16 RNE quantize, store as f32
#pragma unroll
    for (int c = 0; c < 18; ++c)
        out_off[(size_t)b * 18 * HW + (size_t)c * HW + r] =
            __half2float(__float2half(acc[c]));

    // softmax over ch 18..26 (f32), fp16 quantize, store as f32
    float m = acc[18];
#pragma unroll
    for (int c = 19; c < 27; ++c) m = fmaxf(m, acc[c]);
    float e[9], s = 0.f;
#pragma unroll
    for (int k = 0; k < 9; ++k) { e[k] = expf(acc[18 + k] - m); s += e[k]; }
    float inv = 1.f / s;
#pragma unroll
    for (int k = 0; k < 9; ++k)
        out_aff[(size_t)b * 9 * HW + (size_t)k * HW + r] =
            __half2float(__float2half(e[k] * inv));
}

// ---------------------------------------------------------------------------
// Kernel B: one propagation step (modulated deformable 3x3, 1ch) + blend.
// Reads offsets/affinity (already fp16-quantized values, stored f32) from
// the output buffer; frame chain lives in the f32 list_feat region.
// ---------------------------------------------------------------------------
__global__ __launch_bounds__(256) void prop_kernel(
    const float* __restrict__ src,        // [B,H,W] prev frame (f32, exact)
    float* __restrict__ dst,              // [B,H,W] this iter's list slot
    const float* __restrict__ off,        // [B,18,H,W]
    const float* __restrict__ aff,        // [B,9,H,W]
    const float* __restrict__ confidence, // [B,1,H,W]
    const float* __restrict__ feat_fix,   // [B,1,H,W]
    const float* __restrict__ w9,         // [9]
    const float* __restrict__ biasp,      // [1]
    float* __restrict__ out_pred)         // pred slot or nullptr
{
    int p = blockIdx.x * 256 + threadIdx.x;
    if (p >= NPIX) return;
    int b = p / HW;
    int r = p - b * HW;
    int y = r / WW;
    int x = r - y * WW;

    const float* offb = off + (size_t)b * 18 * HW + r;
    const float* affb = aff + (size_t)b * 9 * HW + r;
    const float* sf = src + (size_t)b * HW;

    float acc = 0.f;
#pragma unroll
    for (int k = 0; k < 9; ++k) {
        float dy = offb[(size_t)(2 * k) * HW];
        float dx = offb[(size_t)(2 * k + 1) * HW];
        float af = affb[(size_t)k * HW];
        float py = (float)y + (float)(k / 3 - 1) + dy;
        float px = (float)x + (float)(k % 3 - 1) + dx;
        float y0f = floorf(py), x0f = floorf(px);
        float ty = py - y0f, tx = px - x0f;
        int iy = (int)y0f, ix = (int)x0f;
        bool vy0 = ((unsigned)iy < HH), vy1 = ((unsigned)(iy + 1) < HH);
        bool vx0 = ((unsigned)ix < WW), vx1 = ((unsigned)(ix + 1) < WW);
        float v00 = (vy0 && vx0) ? sf[(size_t)iy * WW + ix] : 0.f;
        float v01 = (vy0 && vx1) ? sf[(size_t)iy * WW + ix + 1] : 0.f;
        float v10 = (vy1 && vx0) ? sf[(size_t)(iy + 1) * WW + ix] : 0.f;
        float v11 = (vy1 && vx1) ? sf[(size_t)(iy + 1) * WW + ix + 1] : 0.f;
        float top = (1.f - tx) * v00 + tx * v01;
        float bot = (1.f - tx) * v10 + tx * v11;
        float sv = (1.f - ty) * top + ty * bot;
        acc += sv * af * w9[k];
    }
    float dc = acc + biasp[0];

    float cf = confidence[p];
    float ff = feat_fix[p];
    float sg = (ff > 0.f) ? 1.f : ((ff < 0.f) ? -1.f : 0.f);
    float conf = sg / (1.f + expf(-cf));
    float fr = (1.f - conf) * dc + conf * ff;

    dst[p] = fr;
    if (out_pred) out_pred[p] = fr;
}

// ---------------------------------------------------------------------------
extern "C" void kernel_launch(void* const* d_in, const int* in_sizes, int n_in,
                              void* d_out, int out_size, void* d_ws, size_t ws_size,
                              hipStream_t stream) {
    const float* feat_init  = (const float*)d_in[0];
    const float* guidance   = (const float*)d_in[1];
    const float* confidence = (const float*)d_in[2];
    const float* feat_fix   = (const float*)d_in[3];
    const float* conv_w     = (const float*)d_in[4];
    const float* conv_b     = (const float*)d_in[5];
    const float* w          = (const float*)d_in[6];
    const float* bias       = (const float*)d_in[7];

    float* outf = (float*)d_out;
    float* out_pred = outf;                         // [B,1,H,W]
    float* out_list = outf + (size_t)NPIX;          // [18,B,1,H,W]
    float* out_off  = outf + (size_t)19 * NPIX;     // [B,18,H,W]
    float* out_aff  = outf + (size_t)37 * NPIX;     // [B,9,H,W]

    int blocks = (NPIX + 255) / 256;
    conv_kernel<<<blocks, 256, 0, stream>>>(guidance, conv_w, conv_b,
                                            out_off, out_aff);
    const float* src = feat_init;
    for (int it = 0; it < NITER; ++it) {
        float* dstf = out_list + (size_t)it * NPIX;  // list slot IS the frame
        prop_kernel<<<blocks, 256, 0, stream>>>(
            src, dstf, out_off, out_aff, confidence, feat_fix, w, bias,
            (it == NITER - 1) ? out_pred : nullptr);
        src = dstf;
    }
}

// Round 4
// 556.613 us; speedup vs baseline: 1.2084x; 1.2084x over previous
//
#include <hip/hip_runtime.h>
#include <hip/hip_fp16.h>

#define HH 352
#define WW 1216
#define HW (HH*WW)
#define NPIX (2*HW)      // 856064
#define NITER 18
#define PACK_BYTES ((size_t)NPIX * 64)

// ---------------------------------------------------------------------------
// 9 taps of one input channel -> 27 output-channel accumulators.
// cw indexed wave-uniformly -> compiler scalarizes weights into SGPRs.
// ---------------------------------------------------------------------------
__device__ __forceinline__ void fma_9x27(const float v[9],
                                         const float* __restrict__ cw,
                                         int ci, float acc[27]) {
#pragma unroll
    for (int t = 0; t < 9; ++t)
#pragma unroll
        for (int co = 0; co < 27; ++co)
            acc[co] = fmaf(v[t], cw[co * 81 + ci * 9 + t], acc[co]);
}

// ---------------------------------------------------------------------------
// Kernel A: 3x3 conv (9->27ch, pad 1) + fp16 quantize + softmax.
// Writes f32 offset1/aff1 outputs, and (optionally) a 64 B/pixel packed
// record: 18 f16 offsets, 9 f16 aff, pad, conf f32, feat_fix f32.
// ---------------------------------------------------------------------------
__global__ __launch_bounds__(256) void conv_pack_kernel(
    const float* __restrict__ g,          // [B,9,H,W]
    const float* __restrict__ cw,         // [27,9,3,3]
    const float* __restrict__ cb,         // [27]
    const float* __restrict__ confidence, // [B,1,H,W]
    const float* __restrict__ feat_fix,   // [B,1,H,W]
    float* __restrict__ out_off,          // [B,18,H,W]
    float* __restrict__ out_aff,          // [B,9,H,W]
    uint4* __restrict__ packed)           // [NPIX][4] or nullptr
{
    int p = blockIdx.x * 256 + threadIdx.x;
    if (p >= NPIX) return;
    int b = p / HW;
    int r = p - b * HW;
    int y = r / WW;
    int x = r - y * WW;

    float acc[27];
#pragma unroll
    for (int co = 0; co < 27; ++co) acc[co] = cb[co];

    const float* gb = g + (size_t)b * 9 * HW;
    bool interior = (y >= 1) & (y <= HH - 2) & (x >= 1) & (x <= WW - 2);
    if (interior) {
        const float* c0 = gb + (size_t)(y - 1) * WW + (x - 1);
        for (int ci = 0; ci < 9; ++ci) {
            const float* cp = c0 + (size_t)ci * HW;
            float v[9];
            v[0] = cp[0];          v[1] = cp[1];          v[2] = cp[2];
            v[3] = cp[WW];         v[4] = cp[WW + 1];     v[5] = cp[WW + 2];
            v[6] = cp[2 * WW];     v[7] = cp[2 * WW + 1]; v[8] = cp[2 * WW + 2];
            fma_9x27(v, cw, ci, acc);
        }
    } else {
        for (int ci = 0; ci < 9; ++ci) {
            const float* cp = gb + (size_t)ci * HW;
            float v[9];
#pragma unroll
            for (int t = 0; t < 9; ++t) {
                int yy = y + t / 3 - 1;
                int xx = x + t % 3 - 1;
                v[t] = ((unsigned)yy < HH && (unsigned)xx < WW)
                           ? cp[(size_t)yy * WW + xx] : 0.f;
            }
            fma_9x27(v, cw, ci, acc);
        }
    }

    // fp16 RNE quantization (reference .half() then .float())
    __half h[28];
#pragma unroll
    for (int c = 0; c < 18; ++c) h[c] = __float2half(acc[c]);

    float m = acc[18];
#pragma unroll
    for (int c = 19; c < 27; ++c) m = fmaxf(m, acc[c]);
    float e[9], s = 0.f;
#pragma unroll
    for (int k = 0; k < 9; ++k) { e[k] = expf(acc[18 + k] - m); s += e[k]; }
    float inv = 1.f / s;
#pragma unroll
    for (int k = 0; k < 9; ++k) h[18 + k] = __float2half(e[k] * inv);
    h[27] = __float2half(0.f);

    // required f32 outputs
#pragma unroll
    for (int c = 0; c < 18; ++c)
        out_off[(size_t)b * 18 * HW + (size_t)c * HW + r] = __half2float(h[c]);
#pragma unroll
    for (int k = 0; k < 9; ++k)
        out_aff[(size_t)b * 9 * HW + (size_t)k * HW + r] = __half2float(h[18 + k]);

    if (packed) {
        float cf = confidence[p];
        float ff = feat_fix[p];
        float sg = (ff > 0.f) ? 1.f : ((ff < 0.f) ? -1.f : 0.f);
        float conf = sg / (1.f + expf(-cf));

        unsigned uu[16];
#pragma unroll
        for (int i = 0; i < 14; ++i)
            uu[i] = (unsigned)__half_as_ushort(h[2 * i]) |
                    ((unsigned)__half_as_ushort(h[2 * i + 1]) << 16);
        uu[14] = __float_as_uint(conf);
        uu[15] = __float_as_uint(ff);

        uint4* dst = packed + (size_t)p * 4;
        dst[0] = make_uint4(uu[0], uu[1], uu[2], uu[3]);
        dst[1] = make_uint4(uu[4], uu[5], uu[6], uu[7]);
        dst[2] = make_uint4(uu[8], uu[9], uu[10], uu[11]);
        dst[3] = make_uint4(uu[12], uu[13], uu[14], uu[15]);
    }
}

// ---------------------------------------------------------------------------
// Kernel B (packed): one propagation step from the 64 B/pixel record.
// ---------------------------------------------------------------------------
__global__ __launch_bounds__(256) void prop_packed_kernel(
    const float* __restrict__ src,   // [B,H,W] prev frame
    float* __restrict__ dst,         // [B,H,W] this iter's list slot
    const uint4* __restrict__ packed,
    const float* __restrict__ w9,    // [9]
    const float* __restrict__ biasp, // [1]
    float* __restrict__ out_pred)    // pred slot or nullptr
{
    int p = blockIdx.x * 256 + threadIdx.x;
    if (p >= NPIX) return;
    int b = p / HW;
    int r = p - b * HW;
    int y = r / WW;
    int x = r - y * WW;

    const uint4* pk = packed + (size_t)p * 4;
    uint4 q0 = pk[0], q1 = pk[1], q2 = pk[2], q3 = pk[3];
    unsigned uu[14] = {q0.x, q0.y, q0.z, q0.w, q1.x, q1.y, q1.z, q1.w,
                       q2.x, q2.y, q2.z, q2.w, q3.x, q3.y};
    float hv[27];
#pragma unroll
    for (int i = 0; i < 13; ++i) {
        hv[2 * i]     = __half2float(__ushort_as_half((unsigned short)(uu[i] & 0xffff)));
        hv[2 * i + 1] = __half2float(__ushort_as_half((unsigned short)(uu[i] >> 16)));
    }
    hv[26] = __half2float(__ushort_as_half((unsigned short)(uu[13] & 0xffff)));
    float conf = __uint_as_float(q3.z);
    float ff   = __uint_as_float(q3.w);

    const float* sf = src + (size_t)b * HW;
    float acc = 0.f;
#pragma unroll
    for (int k = 0; k < 9; ++k) {
        float py = (float)y + (float)(k / 3 - 1) + hv[2 * k];
        float px = (float)x + (float)(k % 3 - 1) + hv[2 * k + 1];
        float y0f = floorf(py), x0f = floorf(px);
        float ty = py - y0f, tx = px - x0f;
        int iy = (int)y0f, ix = (int)x0f;
        bool vy0 = ((unsigned)iy < HH), vy1 = ((unsigned)(iy + 1) < HH);
        bool vx0 = ((unsigned)ix < WW), vx1 = ((unsigned)(ix + 1) < WW);
        float v00 = (vy0 && vx0) ? sf[(size_t)iy * WW + ix] : 0.f;
        float v01 = (vy0 && vx1) ? sf[(size_t)iy * WW + ix + 1] : 0.f;
        float v10 = (vy1 && vx0) ? sf[(size_t)(iy + 1) * WW + ix] : 0.f;
        float v11 = (vy1 && vx1) ? sf[(size_t)(iy + 1) * WW + ix + 1] : 0.f;
        float top = (1.f - tx) * v00 + tx * v01;
        float bot = (1.f - tx) * v10 + tx * v11;
        float sv = (1.f - ty) * top + ty * bot;
        acc = fmaf(sv * hv[18 + k], w9[k], acc);
    }
    float dc = acc + biasp[0];
    float fr = (1.f - conf) * dc + conf * ff;

    dst[p] = fr;
    if (out_pred) out_pred[p] = fr;
}

// ---------------------------------------------------------------------------
// Kernel B (fallback, no ws): reads f32 off/aff planes from the output buf.
// ---------------------------------------------------------------------------
__global__ __launch_bounds__(256) void prop_kernel(
    const float* __restrict__ src,
    float* __restrict__ dst,
    const float* __restrict__ off,
    const float* __restrict__ aff,
    const float* __restrict__ confidence,
    const float* __restrict__ feat_fix,
    const float* __restrict__ w9,
    const float* __restrict__ biasp,
    float* __restrict__ out_pred)
{
    int p = blockIdx.x * 256 + threadIdx.x;
    if (p >= NPIX) return;
    int b = p / HW;
    int r = p - b * HW;
    int y = r / WW;
    int x = r - y * WW;

    const float* offb = off + (size_t)b * 18 * HW + r;
    const float* affb = aff + (size_t)b * 9 * HW + r;
    const float* sf = src + (size_t)b * HW;

    float acc = 0.f;
#pragma unroll
    for (int k = 0; k < 9; ++k) {
        float dy = offb[(size_t)(2 * k) * HW];
        float dx = offb[(size_t)(2 * k + 1) * HW];
        float af = affb[(size_t)k * HW];
        float py = (float)y + (float)(k / 3 - 1) + dy;
        float px = (float)x + (float)(k % 3 - 1) + dx;
        float y0f = floorf(py), x0f = floorf(px);
        float ty = py - y0f, tx = px - x0f;
        int iy = (int)y0f, ix = (int)x0f;
        bool vy0 = ((unsigned)iy < HH), vy1 = ((unsigned)(iy + 1) < HH);
        bool vx0 = ((unsigned)ix < WW), vx1 = ((unsigned)(ix + 1) < WW);
        float v00 = (vy0 && vx0) ? sf[(size_t)iy * WW + ix] : 0.f;
        float v01 = (vy0 && vx1) ? sf[(size_t)iy * WW + ix + 1] : 0.f;
        float v10 = (vy1 && vx0) ? sf[(size_t)(iy + 1) * WW + ix] : 0.f;
        float v11 = (vy1 && vx1) ? sf[(size_t)(iy + 1) * WW + ix + 1] : 0.f;
        float top = (1.f - tx) * v00 + tx * v01;
        float bot = (1.f - tx) * v10 + tx * v11;
        float sv = (1.f - ty) * top + ty * bot;
        acc = fmaf(sv * af, w9[k], acc);
    }
    float dc = acc + biasp[0];

    float cf = confidence[p];
    float ffv = feat_fix[p];
    float sg = (ffv > 0.f) ? 1.f : ((ffv < 0.f) ? -1.f : 0.f);
    float conf = sg / (1.f + expf(-cf));
    float fr = (1.f - conf) * dc + conf * ffv;

    dst[p] = fr;
    if (out_pred) out_pred[p] = fr;
}

// ---------------------------------------------------------------------------
extern "C" void kernel_launch(void* const* d_in, const int* in_sizes, int n_in,
                              void* d_out, int out_size, void* d_ws, size_t ws_size,
                              hipStream_t stream) {
    const float* feat_init  = (const float*)d_in[0];
    const float* guidance   = (const float*)d_in[1];
    const float* confidence = (const float*)d_in[2];
    const float* feat_fix   = (const float*)d_in[3];
    const float* conv_w     = (const float*)d_in[4];
    const float* conv_b     = (const float*)d_in[5];
    const float* w          = (const float*)d_in[6];
    const float* bias       = (const float*)d_in[7];

    float* outf = (float*)d_out;
    float* out_pred = outf;                         // [B,1,H,W]
    float* out_list = outf + (size_t)NPIX;          // [18,B,1,H,W]
    float* out_off  = outf + (size_t)19 * NPIX;     // [B,18,H,W]
    float* out_aff  = outf + (size_t)37 * NPIX;     // [B,9,H,W]

    bool use_pack = (ws_size >= PACK_BYTES);
    uint4* packed = use_pack ? (uint4*)d_ws : nullptr;

    int blocks = (NPIX + 255) / 256;
    conv_pack_kernel<<<blocks, 256, 0, stream>>>(
        guidance, conv_w, conv_b, confidence, feat_fix,
        out_off, out_aff, packed);

    const float* src = feat_init;
    for (int it = 0; it < NITER; ++it) {
        float* dstf = out_list + (size_t)it * NPIX;
        float* predp = (it == NITER - 1) ? out_pred : nullptr;
        if (use_pack) {
            prop_packed_kernel<<<blocks, 256, 0, stream>>>(
                src, dstf, packed, w, bias, predp);
        } else {
            prop_kernel<<<blocks, 256, 0, stream>>>(
                src, dstf, out_off, out_aff, confidence, feat_fix, w, bias, predp);
        }
        src = dstf;
    }
}